// Round 2
// 702.175 us; speedup vs baseline: 1.0596x; 1.0596x over previous
//
#include <hip/hip_runtime.h>
#include <cstdint>

typedef unsigned short u16;
typedef unsigned int u32;
typedef __attribute__((ext_vector_type(8))) __bf16 bf16x8;
typedef __attribute__((ext_vector_type(4))) float f32x4;

// ---------- helpers ----------
__device__ __forceinline__ u32 f2bf_bits(float x) {
    u32 a = __builtin_bit_cast(u32, x);
    a += 0x7FFFu + ((a >> 16) & 1u);   // RNE
    return a >> 16;
}
__device__ __forceinline__ u32 pack2(float lo, float hi) {
    u32 a = __builtin_bit_cast(u32, lo);
    u32 b = __builtin_bit_cast(u32, hi);
    a += 0x7FFFu + ((a >> 16) & 1u);
    b += 0x7FFFu + ((b >> 16) & 1u);
    return (a >> 16) | (b & 0xFFFF0000u);
}

#define LDS_STRIDE 72   // 64 + 8 pad, keeps 16B alignment for b128 ops

// ---------- K_prep: fused {w_lt/w_g transpose, theta projection, stats zero} ----------
// blocks [0,512): transpose w_lt,w_g (512,128) fp32 -> (128,512) bf16
// blocks [512,768): theta proj (2048,512)x(512,128) + bias -> thT A-layout
// block 768: zero LN stats
__global__ __launch_bounds__(256) void k_prep(
    const float* __restrict__ w_lt, const float* __restrict__ w_g,
    u16* __restrict__ wltT, u16* __restrict__ wgT,
    const float* __restrict__ st, const float* __restrict__ w_st,
    const float* __restrict__ b_st, u16* __restrict__ thT,
    float* __restrict__ stats)
{
    __shared__ float sA[8 * 512];
    int bi = blockIdx.x;
    int tid = threadIdx.x;
    if (bi < 512) {
        int idx = bi * 256 + tid;   // 0..131071
        int which = idx >> 16;
        int rem = idx & 65535;
        int nrow = rem >> 9;        // 0..127
        int k = rem & 511;          // 0..511
        const float* src = which ? w_g : w_lt;
        u16* dst = which ? wgT : wltT;
        dst[rem] = (u16)f2bf_bits(src[k * 128 + nrow]);
        return;
    }
    if (bi == 768) {
        if (tid < 16) stats[tid] = 0.f;
        return;
    }
    // ---- theta projection (old k2) ----
    int r0 = (bi - 512) * 8;
    {
        const float4* src = (const float4*)(st + (size_t)r0 * 512);
        float4* dst = (float4*)sA;
        #pragma unroll
        for (int i = 0; i < 4; i++) dst[tid + i * 256] = src[tid + i * 256];
    }
    __syncthreads();
    int d = tid & 127, rh = tid >> 7;
    float acc[4] = {0.f, 0.f, 0.f, 0.f};
    #pragma unroll 4
    for (int k = 0; k < 512; k++) {
        float w = w_st[(size_t)k * 128 + d];
        #pragma unroll
        for (int j = 0; j < 4; j++) acc[j] += sA[(rh + j * 2) * 512 + k] * w;
    }
    float bias = b_st[d];
    #pragma unroll
    for (int j = 0; j < 4; j++) {
        int r = r0 + rh + j * 2;
        int n_idx = r >> 8, s_raw = r & 255;
        int f = s_raw * 128 + d;             // flat index in natural (s,d) storage
        // reshaped Theta[c][s]: c=f>>8, s=f&255 ; store A-operand layout thT[s][c]
        thT[(size_t)n_idx * 32768 + (size_t)(f & 255) * 128 + (f >> 8)] =
            (u16)f2bf_bits(acc[j] + bias);
    }
}

// ---------- K1: lt (32768,512) fp32 x {w_lt,w_g} -> phi,g (32768,128) bf16 ----------
__global__ __launch_bounds__(256, 2) void k1_proj_lt(
    const float* __restrict__ lt,
    const u16* __restrict__ wltT, const u16* __restrict__ wgT,
    const float* __restrict__ b_lt, const float* __restrict__ b_g,
    u16* __restrict__ phi, u16* __restrict__ g)
{
    __shared__ u16 sA[128 * LDS_STRIDE];
    __shared__ u16 sBl[128 * LDS_STRIDE];
    __shared__ u16 sBg[128 * LDS_STRIDE];
    int tid = threadIdx.x;
    int wave = tid >> 6, lane = tid & 63, quad = lane >> 4, lq = lane & 15;
    int m0 = blockIdx.x * 128;
    int srow = tid >> 1, skc = (tid & 1) * 32;

    f32x4 zero = {0.f, 0.f, 0.f, 0.f};
    f32x4 acc[2][2][8];
    for (int p = 0; p < 2; p++)
        for (int mt = 0; mt < 2; mt++)
            for (int nt = 0; nt < 8; nt++) acc[p][mt][nt] = zero;

    for (int ko = 0; ko < 8; ko++) {
        // stage A tile (128 x 64) fp32 -> bf16
        {
            const float4* src = (const float4*)(lt + (size_t)(m0 + srow) * 512 + ko * 64 + skc);
            uint2* dst = (uint2*)&sA[srow * LDS_STRIDE + skc];
            #pragma unroll
            for (int i = 0; i < 8; i++) {
                float4 v = src[i];
                uint2 u; u.x = pack2(v.x, v.y); u.y = pack2(v.z, v.w);
                dst[i] = u;
            }
        }
        // stage weight tiles (already bf16, row = out-channel, k-contiguous)
        {
            const uint4* srcl = (const uint4*)(wltT + srow * 512 + ko * 64 + skc);
            const uint4* srcg = (const uint4*)(wgT  + srow * 512 + ko * 64 + skc);
            uint4* dstl = (uint4*)&sBl[srow * LDS_STRIDE + skc];
            uint4* dstg = (uint4*)&sBg[srow * LDS_STRIDE + skc];
            #pragma unroll
            for (int i = 0; i < 4; i++) { dstl[i] = srcl[i]; dstg[i] = srcg[i]; }
        }
        __syncthreads();
        #pragma unroll
        for (int kk = 0; kk < 2; kk++) {
            bf16x8 a[2], bl[8], bg[8];
            #pragma unroll
            for (int mt = 0; mt < 2; mt++)
                a[mt] = *(const bf16x8*)&sA[(wave * 32 + mt * 16 + lq) * LDS_STRIDE + kk * 32 + quad * 8];
            #pragma unroll
            for (int nt = 0; nt < 8; nt++) {
                bl[nt] = *(const bf16x8*)&sBl[(nt * 16 + lq) * LDS_STRIDE + kk * 32 + quad * 8];
                bg[nt] = *(const bf16x8*)&sBg[(nt * 16 + lq) * LDS_STRIDE + kk * 32 + quad * 8];
            }
            #pragma unroll
            for (int mt = 0; mt < 2; mt++)
                #pragma unroll
                for (int nt = 0; nt < 8; nt++) {
                    acc[0][mt][nt] = __builtin_amdgcn_mfma_f32_16x16x32_bf16(a[mt], bl[nt], acc[0][mt][nt], 0, 0, 0);
                    acc[1][mt][nt] = __builtin_amdgcn_mfma_f32_16x16x32_bf16(a[mt], bg[nt], acc[1][mt][nt], 0, 0, 0);
                }
        }
        __syncthreads();
    }
    // epilogue: C/D layout col=lane&15, row=quad*4+r  (natural (l',d) layout)
    #pragma unroll
    for (int mt = 0; mt < 2; mt++) {
        int mbase = m0 + wave * 32 + mt * 16 + quad * 4;
        #pragma unroll
        for (int nt = 0; nt < 8; nt++) {
            int n = nt * 16 + lq;
            float biasl = b_lt[n], biasg = b_g[n];
            #pragma unroll
            for (int r = 0; r < 4; r++) {
                size_t o = (size_t)(mbase + r) * 128 + n;
                phi[o] = (u16)f2bf_bits(acc[0][mt][nt][r] + biasl);
                g[o]   = (u16)f2bf_bits(acc[1][mt][nt][r] + biasg);
            }
        }
    }
}

// ---------- K_tr: phiT[n][l][c] = phi_flat[n][c*4096 + l]  (PhiR^T, B-operand layout for k3) ----------
__global__ __launch_bounds__(256) void k_tr(const u16* __restrict__ phi, u16* __restrict__ phiT)
{
    __shared__ u16 s[64 * 65];   // stride 65: breaks pow2 bank aliasing for the gather
    int bi = blockIdx.x;         // 1024 = 8 n * 2 ct * 64 lt
    int n_idx = bi >> 7, rem = bi & 127;
    int c0 = (rem >> 6) * 64, l0 = (rem & 63) * 64;
    const u16* src = phi + (size_t)n_idx * 524288;
    u16* dst = phiT + (size_t)n_idx * 524288;
    int t = threadIdx.x;
    #pragma unroll
    for (int i = 0; i < 2; i++) {
        int idx = t + i * 256;        // 0..511
        int row = idx >> 3;           // c_local 0..63
        int col = (idx & 7) * 8;      // l_local base
        uint4 v = *(const uint4*)(src + (size_t)(c0 + row) * 4096 + l0 + col);
        u16 tmp[8];
        *(uint4*)tmp = v;
        #pragma unroll
        for (int j = 0; j < 8; j++) s[row * 65 + col + j] = tmp[j];
    }
    __syncthreads();
    #pragma unroll
    for (int i = 0; i < 2; i++) {
        int idx = t + i * 256;
        int lrow = idx >> 3;          // l_local
        int cb = (idx & 7) * 8;       // c_local base
        u16 tmp[8];
        #pragma unroll
        for (int j = 0; j < 8; j++) tmp[j] = s[(cb + j) * 65 + lrow];
        *(uint4*)(dst + (size_t)(l0 + lrow) * 128 + c0 + cb) = *(uint4*)tmp;
    }
}

// ---------- K3: attn(n,s,l) = Theta^T @ Phi * 1/sqrt(128), fp32 ----------
__global__ __launch_bounds__(256, 2) void k3_attn(
    const u16* __restrict__ thT, const u16* __restrict__ phiT,
    float* __restrict__ attn)
{
    __shared__ u16 sA[128 * LDS_STRIDE];
    __shared__ u16 sB[128 * LDS_STRIDE];
    int tid = threadIdx.x;
    int wave = tid >> 6, lane = tid & 63, quad = lane >> 4, lq = lane & 15;
    int bi = blockIdx.x;
    int n_idx = bi >> 6, rem = bi & 63;
    int m0 = (rem >> 5) * 128;       // s tile
    int l0 = (rem & 31) * 128;       // l tile
    const u16* Ab = thT + (size_t)n_idx * 32768;
    const u16* Bb = phiT + (size_t)n_idx * 524288;   // [l][c] layout
    int srow = tid >> 1, skc = (tid & 1) * 32;

    f32x4 zero = {0.f, 0.f, 0.f, 0.f};
    f32x4 acc[2][8];
    for (int mt = 0; mt < 2; mt++)
        for (int nt = 0; nt < 8; nt++) acc[mt][nt] = zero;

    for (int ko = 0; ko < 2; ko++) {
        const uint4* srcA = (const uint4*)(Ab + (size_t)(m0 + srow) * 128 + ko * 64 + skc);
        const uint4* srcB = (const uint4*)(Bb + (size_t)(l0 + srow) * 128 + ko * 64 + skc);
        uint4* dA = (uint4*)&sA[srow * LDS_STRIDE + skc];
        uint4* dB = (uint4*)&sB[srow * LDS_STRIDE + skc];
        #pragma unroll
        for (int i = 0; i < 4; i++) { dA[i] = srcA[i]; dB[i] = srcB[i]; }
        __syncthreads();
        #pragma unroll
        for (int kk = 0; kk < 2; kk++) {
            bf16x8 a[2], b[8];
            #pragma unroll
            for (int mt = 0; mt < 2; mt++)
                a[mt] = *(const bf16x8*)&sA[(wave * 32 + mt * 16 + lq) * LDS_STRIDE + kk * 32 + quad * 8];
            #pragma unroll
            for (int nt = 0; nt < 8; nt++)
                b[nt] = *(const bf16x8*)&sB[(nt * 16 + lq) * LDS_STRIDE + kk * 32 + quad * 8];
            #pragma unroll
            for (int mt = 0; mt < 2; mt++)
                #pragma unroll
                for (int nt = 0; nt < 8; nt++)
                    acc[mt][nt] = __builtin_amdgcn_mfma_f32_16x16x32_bf16(a[mt], b[nt], acc[mt][nt], 0, 0, 0);
        }
        __syncthreads();
    }
    const float scale = 0.08838834764831845f;
    float* Cb = attn + (size_t)n_idx * 1048576;
    #pragma unroll
    for (int mt = 0; mt < 2; mt++) {
        int mbase = m0 + wave * 32 + mt * 16 + quad * 4;
        #pragma unroll
        for (int nt = 0; nt < 8; nt++) {
            int col = l0 + nt * 16 + lq;
            #pragma unroll
            for (int r = 0; r < 4; r++)
                Cb[(size_t)(mbase + r) * 4096 + col] = acc[mt][nt][r] * scale;
        }
    }
}

// ---------- K4: row softmax STATS over l=4096 (identical reduction tree; p no longer materialized) ----------
__global__ __launch_bounds__(256) void k4_stats(
    const float* __restrict__ attn, float* __restrict__ rowstat)
{
    __shared__ float red[256];
    int r = blockIdx.x;   // 0..2047 = n*256+s
    int tid = threadIdx.x;
    const float4* src = (const float4*)(attn + (size_t)r * 4096);
    float4 vv[4];
    float m = -1e30f;
    #pragma unroll
    for (int i = 0; i < 4; i++) {
        vv[i] = src[i * 256 + tid];
        m = fmaxf(m, fmaxf(fmaxf(vv[i].x, vv[i].y), fmaxf(vv[i].z, vv[i].w)));
    }
    red[tid] = m;
    __syncthreads();
    for (int s = 128; s > 0; s >>= 1) {
        if (tid < s) red[tid] = fmaxf(red[tid], red[tid + s]);
        __syncthreads();
    }
    m = red[0];
    __syncthreads();
    float sum = 0.f;
    #pragma unroll
    for (int i = 0; i < 4; i++) {
        vv[i].x = __expf(vv[i].x - m); vv[i].y = __expf(vv[i].y - m);
        vv[i].z = __expf(vv[i].z - m); vv[i].w = __expf(vv[i].w - m);
        sum += vv[i].x + vv[i].y + vv[i].z + vv[i].w;
    }
    red[tid] = sum;
    __syncthreads();
    for (int s = 128; s > 0; s >>= 1) {
        if (tid < s) red[tid] += red[tid + s];
        __syncthreads();
    }
    if (tid == 0) {
        rowstat[r * 2]     = m;
        rowstat[r * 2 + 1] = 1.0f / red[0];
    }
}

// ---------- K5: o[c][s] = G @ P^T, split-K; P recomputed on the fly from attn+rowstat ----------
__global__ __launch_bounds__(256, 2) void k5_pv(
    const u16* __restrict__ g, const float* __restrict__ attn,
    const float* __restrict__ rowstat,
    float* __restrict__ opart)   // (16 chunks, 8 n, 128 c, 256 s)
{
    __shared__ u16 sA[128 * LDS_STRIDE];
    __shared__ u16 sB[128 * LDS_STRIDE];
    int tid = threadIdx.x;
    int wave = tid >> 6, lane = tid & 63, quad = lane >> 4, lq = lane & 15;
    int bi = blockIdx.x;                 // 0..255
    int n_idx = bi >> 5, rem = bi & 31;
    int kch = rem >> 1, stile = rem & 1;
    int s0 = stile * 128;
    int l_base = kch * 256;
    const u16* Ab = g + (size_t)n_idx * 524288;      // GR[c][l] = flat[c*4096+l]
    int srow = tid >> 1, skc = (tid & 1) * 32;

    // per-thread softmax stats for the attn row this thread stages (fixed across ko)
    int sr_row = n_idx * 256 + s0 + srow;
    float rm   = rowstat[sr_row * 2];
    float rinv = rowstat[sr_row * 2 + 1];
    const float* Brow = attn + (size_t)sr_row * 4096;

    f32x4 zero = {0.f, 0.f, 0.f, 0.f};
    f32x4 acc[2][8];
    for (int mt = 0; mt < 2; mt++)
        for (int nt = 0; nt < 8; nt++) acc[mt][nt] = zero;

    for (int ko = 0; ko < 4; ko++) {
        int l0 = l_base + ko * 64;
        const uint4* srcA = (const uint4*)(Ab + (size_t)srow * 4096 + l0 + skc);
        const float4* srcB = (const float4*)(Brow + l0 + skc);
        uint4* dA = (uint4*)&sA[srow * LDS_STRIDE + skc];
        uint2* dB = (uint2*)&sB[srow * LDS_STRIDE + skc];
        #pragma unroll
        for (int i = 0; i < 4; i++) dA[i] = srcA[i];
        #pragma unroll
        for (int i = 0; i < 8; i++) {
            float4 v = srcB[i];
            uint2 u;
            u.x = pack2(__expf(v.x - rm) * rinv, __expf(v.y - rm) * rinv);
            u.y = pack2(__expf(v.z - rm) * rinv, __expf(v.w - rm) * rinv);
            dB[i] = u;
        }
        __syncthreads();
        #pragma unroll
        for (int kk = 0; kk < 2; kk++) {
            bf16x8 a[2], b[8];
            #pragma unroll
            for (int mt = 0; mt < 2; mt++)
                a[mt] = *(const bf16x8*)&sA[(wave * 32 + mt * 16 + lq) * LDS_STRIDE + kk * 32 + quad * 8];
            #pragma unroll
            for (int nt = 0; nt < 8; nt++)
                b[nt] = *(const bf16x8*)&sB[(nt * 16 + lq) * LDS_STRIDE + kk * 32 + quad * 8];
            #pragma unroll
            for (int mt = 0; mt < 2; mt++)
                #pragma unroll
                for (int nt = 0; nt < 8; nt++)
                    acc[mt][nt] = __builtin_amdgcn_mfma_f32_16x16x32_bf16(a[mt], b[nt], acc[mt][nt], 0, 0, 0);
        }
        __syncthreads();
    }
    float* Cb = opart + (size_t)(kch * 8 + n_idx) * 32768;
    #pragma unroll
    for (int mt = 0; mt < 2; mt++) {
        int cbase = wave * 32 + mt * 16 + quad * 4;
        #pragma unroll
        for (int nt = 0; nt < 8; nt++) {
            int s = s0 + nt * 16 + lq;
            #pragma unroll
            for (int r = 0; r < 4; r++)
                Cb[(size_t)(cbase + r) * 256 + s] = acc[mt][nt][r];
        }
    }
}

// ---------- K5b: reduce 16 split-K partials -> o, accumulate LN stats ----------
__global__ __launch_bounds__(256) void k5b_reduce(
    const float* __restrict__ opart, float* __restrict__ obuf,
    float* __restrict__ stats)
{
    __shared__ float red[256];
    __shared__ float red2[256];
    int tid = threadIdx.x;
    int bi = blockIdx.x;           // 0..127 = n*16 + part
    int n_idx = bi >> 4, part = bi & 15;
    int base = part * 2048;
    float lsum = 0.f, lsq = 0.f;
    for (int j = 0; j < 8; j++) {
        int idx = base + j * 256 + tid;
        float o = 0.f;
        #pragma unroll
        for (int ch = 0; ch < 16; ch++)
            o += opart[(size_t)(ch * 8 + n_idx) * 32768 + idx];
        obuf[(size_t)n_idx * 32768 + idx] = o;
        lsum += o; lsq += o * o;
    }
    red[tid] = lsum; red2[tid] = lsq;
    __syncthreads();
    for (int s = 128; s > 0; s >>= 1) {
        if (tid < s) { red[tid] += red[tid + s]; red2[tid] += red2[tid + s]; }
        __syncthreads();
    }
    if (tid == 0) {
        atomicAdd(&stats[n_idx * 2], red[0]);
        atomicAdd(&stats[n_idx * 2 + 1], red2[0]);
    }
}

// ---------- K7: fused LayerNorm + ReLU + broadcast out_conv, 4x unrolled NT stores ----------
__global__ __launch_bounds__(256) void k7_out(
    const float* __restrict__ obuf, const float* __restrict__ stats,
    const float* __restrict__ gamma, const float* __restrict__ beta,
    const float* __restrict__ w_out, const float* __restrict__ b_out,
    float* __restrict__ out)
{
    int tid = threadIdx.x;
    long long base = (long long)blockIdx.x * 1024;   // float4 units; grid = 32768
    int r0 = blockIdx.x * 8 + (tid >> 7);            // rows handled: r0, r0+2, r0+4, r0+6
    int k4i = tid & 127;                             // invariant across the 4 stores
    int n_idx = r0 >> 15;                            // blocks never straddle n (8 | 32768)
    float sum = stats[n_idx * 2], sq = stats[n_idx * 2 + 1];
    float mean = sum * (1.0f / 32768.0f);
    float var = sq * (1.0f / 32768.0f) - mean * mean;
    float rstd = rsqrtf(var + 1e-3f);
    const f32x4* w4p = (const f32x4*)w_out;
    const f32x4* b4p = (const f32x4*)b_out;
    f32x4 w4 = w4p[k4i];
    f32x4 b4 = b4p[k4i];
    f32x4* out4 = (f32x4*)out;
    #pragma unroll
    for (int i = 0; i < 4; i++) {
        int row = r0 + i * 2;
        int ridx = row & 32767;
        float o = obuf[row];
        float v = (o - mean) * rstd * gamma[ridx] + beta[ridx];
        v = fmaxf(v, 0.f);
        f32x4 r;
        r.x = __builtin_fmaf(v, w4.x, b4.x);
        r.y = __builtin_fmaf(v, w4.y, b4.y);
        r.z = __builtin_fmaf(v, w4.z, b4.z);
        r.w = __builtin_fmaf(v, w4.w, b4.w);
        __builtin_nontemporal_store(r, &out4[base + tid + i * 256]);
    }
}

// ---------- launch ----------
extern "C" void kernel_launch(void* const* d_in, const int* in_sizes, int n_in,
                              void* d_out, int out_size, void* d_ws, size_t ws_size,
                              hipStream_t stream)
{
    (void)in_sizes; (void)n_in; (void)out_size; (void)ws_size;
    const float* st    = (const float*)d_in[0];
    const float* lt    = (const float*)d_in[1];
    const float* w_st  = (const float*)d_in[2];
    const float* b_st  = (const float*)d_in[3];
    const float* w_lt  = (const float*)d_in[4];
    const float* b_lt  = (const float*)d_in[5];
    const float* w_g   = (const float*)d_in[6];
    const float* b_g   = (const float*)d_in[7];
    const float* gamma = (const float*)d_in[8];
    const float* beta  = (const float*)d_in[9];
    const float* w_out = (const float*)d_in[10];
    const float* b_out = (const float*)d_in[11];

    char* ws = (char*)d_ws;
    u16*   phi    = (u16*)  (ws + 0);          //  8,388,608 B
    u16*   gbuf   = (u16*)  (ws + 8388608);    //  8,388,608
    u16*   thT    = (u16*)  (ws + 16777216);   //    524,288
    u16*   wltT   = (u16*)  (ws + 17301504);   //    131,072
    u16*   wgT    = (u16*)  (ws + 17432576);   //    131,072
    float* attn   = (float*)(ws + 17563648);   // 33,554,432
    float* rowstat= (float*)(ws + 51118080);   //     16,384 (was pbuf, now stats-only)
    float* opart  = (float*)(ws + 67895296);   // 16,777,216
    float* obuf   = (float*)(ws + 84672512);   //  1,048,576
    float* stats  = (float*)(ws + 85721088);   //         64
    // phiT aliases opart: live only between k_tr and k3; opart first written at k5
    u16*   phiT   = (u16*)opart;               //  8,388,608 (of opart's 16 MB)

    k_prep     <<<769,   256, 0, stream>>>(w_lt, w_g, wltT, wgT, st, w_st, b_st, thT, stats);
    k1_proj_lt <<<256,   256, 0, stream>>>(lt, wltT, wgT, b_lt, b_g, phi, gbuf);
    k_tr       <<<1024,  256, 0, stream>>>(phi, phiT);
    k3_attn    <<<512,   256, 0, stream>>>(thT, phiT, attn);
    k4_stats   <<<2048,  256, 0, stream>>>(attn, rowstat);
    k5_pv      <<<256,   256, 0, stream>>>(gbuf, attn, rowstat, opart);
    k5b_reduce <<<128,   256, 0, stream>>>(opart, obuf, stats);
    k7_out     <<<32768, 256, 0, stream>>>(obuf, stats, gamma, beta, w_out, b_out,
                                           (float*)d_out);
}

// Round 4
// 695.686 us; speedup vs baseline: 1.0695x; 1.0093x over previous
//
#include <hip/hip_runtime.h>
#include <cstdint>

typedef unsigned short u16;
typedef unsigned int u32;
typedef __attribute__((ext_vector_type(8))) __bf16 bf16x8;
typedef __attribute__((ext_vector_type(4))) float f32x4;

// ---------- helpers ----------
__device__ __forceinline__ u32 f2bf_bits(float x) {
    u32 a = __builtin_bit_cast(u32, x);
    a += 0x7FFFu + ((a >> 16) & 1u);   // RNE
    return a >> 16;
}
__device__ __forceinline__ u32 pack2(float lo, float hi) {
    u32 a = __builtin_bit_cast(u32, lo);
    u32 b = __builtin_bit_cast(u32, hi);
    a += 0x7FFFu + ((a >> 16) & 1u);
    b += 0x7FFFu + ((b >> 16) & 1u);
    return (a >> 16) | (b & 0xFFFF0000u);
}

#define LDS_STRIDE 72   // 64 + 8 pad, keeps 16B alignment for b128 ops

// ---------- K_wt: weight transpose + stats zero ----------
// blocks [0,512): transpose w_lt,w_g (512,128) fp32 -> (128,512) bf16
// block 512: zero LN stats
__global__ __launch_bounds__(256) void k_wt(
    const float* __restrict__ w_lt, const float* __restrict__ w_g,
    u16* __restrict__ wltT, u16* __restrict__ wgT,
    float* __restrict__ stats)
{
    int bi = blockIdx.x;
    int tid = threadIdx.x;
    if (bi == 512) {
        if (tid < 16) stats[tid] = 0.f;
        return;
    }
    int idx = bi * 256 + tid;   // 0..131071
    int which = idx >> 16;
    int rem = idx & 65535;
    int nrow = rem >> 9;        // 0..127
    int k = rem & 511;          // 0..511
    const float* src = which ? w_g : w_lt;
    u16* dst = which ? wgT : wltT;
    dst[rem] = (u16)f2bf_bits(src[k * 128 + nrow]);
}

// ---------- K1: blocks [0,256): lt GEMM -> phi,g ; blocks [256,512): theta proj ----------
__global__ __launch_bounds__(256, 2) void k1_proj_lt(
    const float* __restrict__ lt,
    const u16* __restrict__ wltT, const u16* __restrict__ wgT,
    const float* __restrict__ b_lt, const float* __restrict__ b_g,
    u16* __restrict__ phi, u16* __restrict__ g,
    const float* __restrict__ st, const float* __restrict__ w_st,
    const float* __restrict__ b_st, u16* __restrict__ thT)
{
    __shared__ __align__(16) u16 sA[128 * LDS_STRIDE];
    __shared__ u16 sBl[128 * LDS_STRIDE];
    __shared__ u16 sBg[128 * LDS_STRIDE];
    int tid = threadIdx.x;
    int bi = blockIdx.x;

    if (bi >= 256) {
        // ---- theta projection (independent of GEMM; overlaps with it) ----
        float* sT = (float*)sA;    // 16384 B <= 18432 B
        int r0 = (bi - 256) * 8;
        {
            const float4* src = (const float4*)(st + (size_t)r0 * 512);
            float4* dst = (float4*)sT;
            #pragma unroll
            for (int i = 0; i < 4; i++) dst[tid + i * 256] = src[tid + i * 256];
        }
        __syncthreads();
        int d = tid & 127, rh = tid >> 7;
        float acc[4] = {0.f, 0.f, 0.f, 0.f};
        #pragma unroll 4
        for (int k = 0; k < 512; k++) {
            float w = w_st[(size_t)k * 128 + d];
            #pragma unroll
            for (int j = 0; j < 4; j++) acc[j] += sT[(rh + j * 2) * 512 + k] * w;
        }
        float bias = b_st[d];
        #pragma unroll
        for (int j = 0; j < 4; j++) {
            int r = r0 + rh + j * 2;
            int n_idx = r >> 8;
            int f = (r & 255) * 128 + d;     // flat index in natural (s,d) storage
            // reshaped Theta[c][s]: c=f>>8, s=f&255 ; store A-operand layout thT[s][c]
            thT[(size_t)n_idx * 32768 + (size_t)(f & 255) * 128 + (f >> 8)] =
                (u16)f2bf_bits(acc[j] + bias);
        }
        return;
    }

    // ---- GEMM path ----
    int wave = tid >> 6, lane = tid & 63, quad = lane >> 4, lq = lane & 15;
    int m0 = bi * 128;
    int srow = tid >> 1, skc = (tid & 1) * 32;

    f32x4 zero = {0.f, 0.f, 0.f, 0.f};
    f32x4 acc[2][2][8];
    for (int p = 0; p < 2; p++)
        for (int mt = 0; mt < 2; mt++)
            for (int nt = 0; nt < 8; nt++) acc[p][mt][nt] = zero;

    for (int ko = 0; ko < 8; ko++) {
        // stage A tile (128 x 64) fp32 -> bf16
        {
            const float4* src = (const float4*)(lt + (size_t)(m0 + srow) * 512 + ko * 64 + skc);
            uint2* dst = (uint2*)&sA[srow * LDS_STRIDE + skc];
            #pragma unroll
            for (int i = 0; i < 8; i++) {
                float4 v = src[i];
                uint2 u; u.x = pack2(v.x, v.y); u.y = pack2(v.z, v.w);
                dst[i] = u;
            }
        }
        // stage weight tiles (already bf16, row = out-channel, k-contiguous)
        {
            const uint4* srcl = (const uint4*)(wltT + srow * 512 + ko * 64 + skc);
            const uint4* srcg = (const uint4*)(wgT  + srow * 512 + ko * 64 + skc);
            uint4* dstl = (uint4*)&sBl[srow * LDS_STRIDE + skc];
            uint4* dstg = (uint4*)&sBg[srow * LDS_STRIDE + skc];
            #pragma unroll
            for (int i = 0; i < 4; i++) { dstl[i] = srcl[i]; dstg[i] = srcg[i]; }
        }
        __syncthreads();
        #pragma unroll
        for (int kk = 0; kk < 2; kk++) {
            bf16x8 a[2], bl[8], bg[8];
            #pragma unroll
            for (int mt = 0; mt < 2; mt++)
                a[mt] = *(const bf16x8*)&sA[(wave * 32 + mt * 16 + lq) * LDS_STRIDE + kk * 32 + quad * 8];
            #pragma unroll
            for (int nt = 0; nt < 8; nt++) {
                bl[nt] = *(const bf16x8*)&sBl[(nt * 16 + lq) * LDS_STRIDE + kk * 32 + quad * 8];
                bg[nt] = *(const bf16x8*)&sBg[(nt * 16 + lq) * LDS_STRIDE + kk * 32 + quad * 8];
            }
            #pragma unroll
            for (int mt = 0; mt < 2; mt++)
                #pragma unroll
                for (int nt = 0; nt < 8; nt++) {
                    acc[0][mt][nt] = __builtin_amdgcn_mfma_f32_16x16x32_bf16(a[mt], bl[nt], acc[0][mt][nt], 0, 0, 0);
                    acc[1][mt][nt] = __builtin_amdgcn_mfma_f32_16x16x32_bf16(a[mt], bg[nt], acc[1][mt][nt], 0, 0, 0);
                }
        }
        __syncthreads();
    }
    // epilogue: C/D layout col=lane&15, row=quad*4+r  (natural (l',d) layout)
    #pragma unroll
    for (int mt = 0; mt < 2; mt++) {
        int mbase = m0 + wave * 32 + mt * 16 + quad * 4;
        #pragma unroll
        for (int nt = 0; nt < 8; nt++) {
            int n = nt * 16 + lq;
            float biasl = b_lt[n], biasg = b_g[n];
            #pragma unroll
            for (int r = 0; r < 4; r++) {
                size_t o = (size_t)(mbase + r) * 128 + n;
                phi[o] = (u16)f2bf_bits(acc[0][mt][nt][r] + biasl);
                g[o]   = (u16)f2bf_bits(acc[1][mt][nt][r] + biasg);
            }
        }
    }
}

// ---------- K_tr: phiT[n][l][c] = phi_flat[n][c*4096 + l]  (PhiR^T, B-operand layout for k3) ----------
__global__ __launch_bounds__(256) void k_tr(const u16* __restrict__ phi, u16* __restrict__ phiT)
{
    __shared__ u16 s[64 * 65];   // stride 65: breaks pow2 bank aliasing for the gather
    int bi = blockIdx.x;         // 1024 = 8 n * 2 ct * 64 lt
    int n_idx = bi >> 7, rem = bi & 127;
    int c0 = (rem >> 6) * 64, l0 = (rem & 63) * 64;
    const u16* src = phi + (size_t)n_idx * 524288;
    u16* dst = phiT + (size_t)n_idx * 524288;
    int t = threadIdx.x;
    #pragma unroll
    for (int i = 0; i < 2; i++) {
        int idx = t + i * 256;        // 0..511
        int row = idx >> 3;           // c_local 0..63
        int col = (idx & 7) * 8;      // l_local base
        uint4 v = *(const uint4*)(src + (size_t)(c0 + row) * 4096 + l0 + col);
        u16 tmp[8];
        *(uint4*)tmp = v;
        #pragma unroll
        for (int j = 0; j < 8; j++) s[row * 65 + col + j] = tmp[j];
    }
    __syncthreads();
    #pragma unroll
    for (int i = 0; i < 2; i++) {
        int idx = t + i * 256;
        int lrow = idx >> 3;          // l_local
        int cb = (idx & 7) * 8;       // c_local base
        u16 tmp[8];
        #pragma unroll
        for (int j = 0; j < 8; j++) tmp[j] = s[(cb + j) * 65 + lrow];
        *(uint4*)(dst + (size_t)(l0 + lrow) * 128 + c0 + cb) = *(uint4*)tmp;
    }
}

// ---------- K3: attn(n,s,l) = Theta^T @ Phi * 1/sqrt(128), fp32 ----------
__global__ __launch_bounds__(256, 2) void k3_attn(
    const u16* __restrict__ thT, const u16* __restrict__ phiT,
    float* __restrict__ attn)
{
    __shared__ u16 sA[128 * LDS_STRIDE];
    __shared__ u16 sB[128 * LDS_STRIDE];
    int tid = threadIdx.x;
    int wave = tid >> 6, lane = tid & 63, quad = lane >> 4, lq = lane & 15;
    int bi = blockIdx.x;
    int n_idx = bi >> 6, rem = bi & 63;
    int m0 = (rem >> 5) * 128;       // s tile
    int l0 = (rem & 31) * 128;       // l tile
    const u16* Ab = thT + (size_t)n_idx * 32768;
    const u16* Bb = phiT + (size_t)n_idx * 524288;   // [l][c] layout
    int srow = tid >> 1, skc = (tid & 1) * 32;

    f32x4 zero = {0.f, 0.f, 0.f, 0.f};
    f32x4 acc[2][8];
    for (int mt = 0; mt < 2; mt++)
        for (int nt = 0; nt < 8; nt++) acc[mt][nt] = zero;

    for (int ko = 0; ko < 2; ko++) {
        const uint4* srcA = (const uint4*)(Ab + (size_t)(m0 + srow) * 128 + ko * 64 + skc);
        const uint4* srcB = (const uint4*)(Bb + (size_t)(l0 + srow) * 128 + ko * 64 + skc);
        uint4* dA = (uint4*)&sA[srow * LDS_STRIDE + skc];
        uint4* dB = (uint4*)&sB[srow * LDS_STRIDE + skc];
        #pragma unroll
        for (int i = 0; i < 4; i++) { dA[i] = srcA[i]; dB[i] = srcB[i]; }
        __syncthreads();
        #pragma unroll
        for (int kk = 0; kk < 2; kk++) {
            bf16x8 a[2], b[8];
            #pragma unroll
            for (int mt = 0; mt < 2; mt++)
                a[mt] = *(const bf16x8*)&sA[(wave * 32 + mt * 16 + lq) * LDS_STRIDE + kk * 32 + quad * 8];
            #pragma unroll
            for (int nt = 0; nt < 8; nt++)
                b[nt] = *(const bf16x8*)&sB[(nt * 16 + lq) * LDS_STRIDE + kk * 32 + quad * 8];
            #pragma unroll
            for (int mt = 0; mt < 2; mt++)
                #pragma unroll
                for (int nt = 0; nt < 8; nt++)
                    acc[mt][nt] = __builtin_amdgcn_mfma_f32_16x16x32_bf16(a[mt], b[nt], acc[mt][nt], 0, 0, 0);
        }
        __syncthreads();
    }
    const float scale = 0.08838834764831845f;
    float* Cb = attn + (size_t)n_idx * 1048576;
    #pragma unroll
    for (int mt = 0; mt < 2; mt++) {
        int mbase = m0 + wave * 32 + mt * 16 + quad * 4;
        #pragma unroll
        for (int nt = 0; nt < 8; nt++) {
            int col = l0 + nt * 16 + lq;
            #pragma unroll
            for (int r = 0; r < 4; r++)
                Cb[(size_t)(mbase + r) * 4096 + col] = acc[mt][nt][r] * scale;
        }
    }
}

// ---------- K4: row softmax STATS over l=4096 (exact-order tree: LDS for s>=64, shfl for s<=32) ----------
__global__ __launch_bounds__(256) void k4_stats(
    const float* __restrict__ attn, float* __restrict__ rowstat)
{
    __shared__ float red[256];
    int r = blockIdx.x;   // 0..2047 = n*256+s
    int tid = threadIdx.x;
    const float4* src = (const float4*)(attn + (size_t)r * 4096);
    float4 vv[4];
    float m = -1e30f;
    #pragma unroll
    for (int i = 0; i < 4; i++) {
        vv[i] = src[i * 256 + tid];
        m = fmaxf(m, fmaxf(fmaxf(vv[i].x, vv[i].y), fmaxf(vv[i].z, vv[i].w)));
    }
    red[tid] = m;
    __syncthreads();
    if (tid < 128) red[tid] = fmaxf(red[tid], red[tid + 128]);
    __syncthreads();
    if (tid < 64) {
        float v = fmaxf(red[tid], red[tid + 64]);
        #pragma unroll
        for (int s = 32; s > 0; s >>= 1) v = fmaxf(v, __shfl_down(v, s));
        if (tid == 0) red[0] = v;
    }
    __syncthreads();
    m = red[0];
    __syncthreads();   // red[0] must be read by all before red[] is overwritten
    float sum = 0.f;
    #pragma unroll
    for (int i = 0; i < 4; i++) {
        vv[i].x = __expf(vv[i].x - m); vv[i].y = __expf(vv[i].y - m);
        vv[i].z = __expf(vv[i].z - m); vv[i].w = __expf(vv[i].w - m);
        sum += vv[i].x + vv[i].y + vv[i].z + vv[i].w;
    }
    red[tid] = sum;
    __syncthreads();
    if (tid < 128) red[tid] += red[tid + 128];
    __syncthreads();
    if (tid < 64) {
        float v = red[tid] + red[tid + 64];
        #pragma unroll
        for (int s = 32; s > 0; s >>= 1) v += __shfl_down(v, s);
        if (tid == 0) {
            rowstat[r * 2]     = m;
            rowstat[r * 2 + 1] = 1.0f / v;
        }
    }
}

// ---------- K5: o[c][s] = G @ P^T, split-K (32 chunks of 128 over l); P recomputed on the fly ----------
__global__ __launch_bounds__(256, 2) void k5_pv(
    const u16* __restrict__ g, const float* __restrict__ attn,
    const float* __restrict__ rowstat,
    float* __restrict__ opart)   // (32 chunks, 8 n, 128 c, 256 s)
{
    __shared__ u16 sA[128 * LDS_STRIDE];
    __shared__ u16 sB[128 * LDS_STRIDE];
    int tid = threadIdx.x;
    int wave = tid >> 6, lane = tid & 63, quad = lane >> 4, lq = lane & 15;
    int bi = blockIdx.x;                 // 0..511
    int n_idx = bi >> 6, rem = bi & 63;
    int kch = rem >> 1, stile = rem & 1; // 32 chunks x 2 s-tiles
    int s0 = stile * 128;
    int l_base = kch * 128;
    const u16* Ab = g + (size_t)n_idx * 524288;      // GR[c][l] = flat[c*4096+l]
    int srow = tid >> 1, skc = (tid & 1) * 32;

    // per-thread softmax stats for the attn row this thread stages (fixed across ko)
    int sr_row = n_idx * 256 + s0 + srow;
    float rm   = rowstat[sr_row * 2];
    float rinv = rowstat[sr_row * 2 + 1];
    const float* Brow = attn + (size_t)sr_row * 4096;

    f32x4 zero = {0.f, 0.f, 0.f, 0.f};
    f32x4 acc[2][8];
    for (int mt = 0; mt < 2; mt++)
        for (int nt = 0; nt < 8; nt++) acc[mt][nt] = zero;

    for (int ko = 0; ko < 2; ko++) {
        int l0 = l_base + ko * 64;
        const uint4* srcA = (const uint4*)(Ab + (size_t)srow * 4096 + l0 + skc);
        const float4* srcB = (const float4*)(Brow + l0 + skc);
        uint4* dA = (uint4*)&sA[srow * LDS_STRIDE + skc];
        uint2* dB = (uint2*)&sB[srow * LDS_STRIDE + skc];
        #pragma unroll
        for (int i = 0; i < 4; i++) dA[i] = srcA[i];
        #pragma unroll
        for (int i = 0; i < 8; i++) {
            float4 v = srcB[i];
            uint2 u;
            u.x = pack2(__expf(v.x - rm) * rinv, __expf(v.y - rm) * rinv);
            u.y = pack2(__expf(v.z - rm) * rinv, __expf(v.w - rm) * rinv);
            dB[i] = u;
        }
        __syncthreads();
        #pragma unroll
        for (int kk = 0; kk < 2; kk++) {
            bf16x8 a[2], b[8];
            #pragma unroll
            for (int mt = 0; mt < 2; mt++)
                a[mt] = *(const bf16x8*)&sA[(wave * 32 + mt * 16 + lq) * LDS_STRIDE + kk * 32 + quad * 8];
            #pragma unroll
            for (int nt = 0; nt < 8; nt++)
                b[nt] = *(const bf16x8*)&sB[(nt * 16 + lq) * LDS_STRIDE + kk * 32 + quad * 8];
            #pragma unroll
            for (int mt = 0; mt < 2; mt++)
                #pragma unroll
                for (int nt = 0; nt < 8; nt++)
                    acc[mt][nt] = __builtin_amdgcn_mfma_f32_16x16x32_bf16(a[mt], b[nt], acc[mt][nt], 0, 0, 0);
        }
        __syncthreads();
    }
    float* Cb = opart + (size_t)(kch * 8 + n_idx) * 32768;
    #pragma unroll
    for (int mt = 0; mt < 2; mt++) {
        int cbase = wave * 32 + mt * 16 + quad * 4;
        #pragma unroll
        for (int nt = 0; nt < 8; nt++) {
            int s = s0 + nt * 16 + lq;
            #pragma unroll
            for (int r = 0; r < 4; r++)
                Cb[(size_t)(cbase + r) * 256 + s] = acc[mt][nt][r];
        }
    }
}

// ---------- K5b: reduce 32 split-K partials -> o, accumulate LN stats ----------
__global__ __launch_bounds__(256) void k5b_reduce(
    const float* __restrict__ opart, float* __restrict__ obuf,
    float* __restrict__ stats)
{
    __shared__ float red[256];
    __shared__ float red2[256];
    int tid = threadIdx.x;
    int bi = blockIdx.x;           // 0..511 = n*64 + part
    int n_idx = bi >> 6, part = bi & 63;
    int base = part * 512;
    float lsum = 0.f, lsq = 0.f;
    #pragma unroll
    for (int j = 0; j < 2; j++) {
        int idx = base + j * 256 + tid;
        float o = 0.f;
        #pragma unroll
        for (int ch = 0; ch < 32; ch++)
            o += opart[(size_t)(ch * 8 + n_idx) * 32768 + idx];
        obuf[(size_t)n_idx * 32768 + idx] = o;
        lsum += o; lsq += o * o;
    }
    red[tid] = lsum; red2[tid] = lsq;
    __syncthreads();
    if (tid < 128) { red[tid] += red[tid + 128]; red2[tid] += red2[tid + 128]; }
    __syncthreads();
    if (tid < 64) {
        float v = red[tid] + red[tid + 64];
        float v2 = red2[tid] + red2[tid + 64];
        #pragma unroll
        for (int s = 32; s > 0; s >>= 1) {
            v  += __shfl_down(v, s);
            v2 += __shfl_down(v2, s);
        }
        if (tid == 0) {
            atomicAdd(&stats[n_idx * 2], v);
            atomicAdd(&stats[n_idx * 2 + 1], v2);
        }
    }
}

// ---------- K7: fused LayerNorm + ReLU + broadcast out_conv, 4x unrolled NT stores ----------
__global__ __launch_bounds__(256) void k7_out(
    const float* __restrict__ obuf, const float* __restrict__ stats,
    const float* __restrict__ gamma, const float* __restrict__ beta,
    const float* __restrict__ w_out, const float* __restrict__ b_out,
    float* __restrict__ out)
{
    int tid = threadIdx.x;
    long long base = (long long)blockIdx.x * 1024;   // float4 units; grid = 32768
    int r0 = blockIdx.x * 8 + (tid >> 7);            // rows handled: r0, r0+2, r0+4, r0+6
    int k4i = tid & 127;                             // invariant across the 4 stores
    int n_idx = r0 >> 15;                            // blocks never straddle n (8 | 32768)
    float sum = stats[n_idx * 2], sq = stats[n_idx * 2 + 1];
    float mean = sum * (1.0f / 32768.0f);
    float var = sq * (1.0f / 32768.0f) - mean * mean;
    float rstd = rsqrtf(var + 1e-3f);
    const f32x4* w4p = (const f32x4*)w_out;
    const f32x4* b4p = (const f32x4*)b_out;
    f32x4 w4 = w4p[k4i];
    f32x4 b4 = b4p[k4i];
    f32x4* out4 = (f32x4*)out;
    #pragma unroll
    for (int i = 0; i < 4; i++) {
        int row = r0 + i * 2;
        int ridx = row & 32767;
        float o = obuf[row];
        float v = (o - mean) * rstd * gamma[ridx] + beta[ridx];
        v = fmaxf(v, 0.f);
        f32x4 r;
        r.x = __builtin_fmaf(v, w4.x, b4.x);
        r.y = __builtin_fmaf(v, w4.y, b4.y);
        r.z = __builtin_fmaf(v, w4.z, b4.z);
        r.w = __builtin_fmaf(v, w4.w, b4.w);
        __builtin_nontemporal_store(r, &out4[base + tid + i * 256]);
    }
}

// ---------- launch ----------
extern "C" void kernel_launch(void* const* d_in, const int* in_sizes, int n_in,
                              void* d_out, int out_size, void* d_ws, size_t ws_size,
                              hipStream_t stream)
{
    (void)in_sizes; (void)n_in; (void)out_size; (void)ws_size;
    const float* st    = (const float*)d_in[0];
    const float* lt    = (const float*)d_in[1];
    const float* w_st  = (const float*)d_in[2];
    const float* b_st  = (const float*)d_in[3];
    const float* w_lt  = (const float*)d_in[4];
    const float* b_lt  = (const float*)d_in[5];
    const float* w_g   = (const float*)d_in[6];
    const float* b_g   = (const float*)d_in[7];
    const float* gamma = (const float*)d_in[8];
    const float* beta  = (const float*)d_in[9];
    const float* w_out = (const float*)d_in[10];
    const float* b_out = (const float*)d_in[11];

    char* ws = (char*)d_ws;
    u16*   phi    = (u16*)  (ws + 0);          //  8,388,608 B
    u16*   gbuf   = (u16*)  (ws + 8388608);    //  8,388,608
    u16*   thT    = (u16*)  (ws + 16777216);   //    524,288
    u16*   wltT   = (u16*)  (ws + 17301504);   //    131,072
    u16*   wgT    = (u16*)  (ws + 17432576);   //    131,072
    float* attn   = (float*)(ws + 17563648);   // 33,554,432
    float* rowstat= (float*)(ws + 51118080);   //     16,384
    float* opart  = (float*)(ws + 51134464);   // 33,554,432 (32 chunks)
    float* obuf   = (float*)(ws + 84688896);   //  1,048,576
    float* stats  = (float*)(ws + 85737472);   //         64
    // phiT aliases opart: live only between k_tr and k3; opart first written at k5
    u16*   phiT   = (u16*)opart;               //  8,388,608 (of opart's 33.5 MB)

    k_wt       <<<513,   256, 0, stream>>>(w_lt, w_g, wltT, wgT, stats);
    k1_proj_lt <<<512,   256, 0, stream>>>(lt, wltT, wgT, b_lt, b_g, phi, gbuf,
                                           st, w_st, b_st, thT);
    k_tr       <<<1024,  256, 0, stream>>>(phi, phiT);
    k3_attn    <<<512,   256, 0, stream>>>(thT, phiT, attn);
    k4_stats   <<<2048,  256, 0, stream>>>(attn, rowstat);
    k5_pv      <<<512,   256, 0, stream>>>(gbuf, attn, rowstat, opart);
    k5b_reduce <<<512,   256, 0, stream>>>(opart, obuf, stats);
    k7_out     <<<32768, 256, 0, stream>>>(obuf, stats, gamma, beta, w_out, b_out,
                                           (float*)d_out);
}